// Round 1
// baseline (58.923 us; speedup 1.0000x reference)
//
#include <hip/hip_runtime.h>

// Problem constants (from reference setup_inputs):
//   logits: (N=4, C=19, H=512, W=1024) float32, target unused.
#define NCLS 19
#define NSMP 4
#define HW   (512 * 1024)
#define NSEG (NSMP * NCLS)   // 76 segments

// ws layout (floats): [0..NSEG) = S1, [NSEG..2*NSEG) = S2, [2*NSEG..3*NSEG) = cnt
__global__ void cl_init_ws(float* ws) {
    int i = threadIdx.x;
    if (i < 3 * NSEG) ws[i] = 0.0f;
}

__global__ __launch_bounds__(256) void cl_main(const float* __restrict__ logits,
                                               float* __restrict__ ws) {
    __shared__ float sS1[NCLS];
    __shared__ float sS2[NCLS];
    __shared__ float sCnt[NCLS];
    const int tid = threadIdx.x;
    if (tid < NCLS) { sS1[tid] = 0.0f; sS2[tid] = 0.0f; sCnt[tid] = 0.0f; }
    __syncthreads();

    // 4 consecutive pixels per thread; 1024 pixels per block.
    // HW % 1024 == 0, so every block lies within a single sample n.
    const long long p   = ((long long)blockIdx.x * 256 + tid) * 4;  // pixel idx in N*HW
    const int       n   = (int)(p / HW);
    const long long off = p - (long long)n * HW;
    const float* base = logits + (size_t)n * NCLS * HW + off;

    float s1[4], s2[4], mv[4];
    int   mi[4];

    // c = 0
    float4 v = *(const float4*)(base);
    {
        const float a0[4] = {v.x, v.y, v.z, v.w};
        #pragma unroll
        for (int j = 0; j < 4; ++j) {
            s1[j] = a0[j];
            s2[j] = a0[j] * a0[j];
            mv[j] = a0[j];
            mi[j] = 0;
        }
    }
    #pragma unroll
    for (int c = 1; c < NCLS; ++c) {
        float4 u = *(const float4*)(base + (size_t)c * HW);
        const float a[4] = {u.x, u.y, u.z, u.w};
        #pragma unroll
        for (int j = 0; j < 4; ++j) {
            s1[j] += a[j];
            s2[j] += a[j] * a[j];
            if (a[j] > mv[j]) { mv[j] = a[j]; mi[j] = c; }  // strict > keeps first-index argmax
        }
    }

    #pragma unroll
    for (int j = 0; j < 4; ++j) {
        atomicAdd(&sS1[mi[j]],  s1[j]);
        atomicAdd(&sS2[mi[j]],  s2[j]);
        atomicAdd(&sCnt[mi[j]], 1.0f);
    }
    __syncthreads();

    if (tid < NCLS) {
        const int seg = n * NCLS + tid;
        atomicAdd(&ws[seg],            sS1[tid]);
        atomicAdd(&ws[NSEG + seg],     sS2[tid]);
        atomicAdd(&ws[2 * NSEG + seg], sCnt[tid]);
    }
}

__global__ void cl_final(const float* __restrict__ ws, float* __restrict__ out) {
    __shared__ float red[128];
    const int i = threadIdx.x;
    float v = 0.0f;
    if (i < NSEG) {
        const float S1  = ws[i];
        const float S2  = ws[NSEG + i];
        const float cnt = ws[2 * NSEG + i];
        const float K   = fmaxf(cnt, 1.0f) * (float)NCLS;
        const float sq  = fmaxf(S2 - S1 * S1 / K, 0.0f);
        v = (cnt > 0.0f) ? sqrtf(sq) : 0.0f;
    }
    red[i] = v;
    __syncthreads();
    #pragma unroll
    for (int s = 64; s > 0; s >>= 1) {
        if (i < s) red[i] += red[i + s];
        __syncthreads();
    }
    if (i == 0) out[0] = red[0] / (float)NSMP;
}

extern "C" void kernel_launch(void* const* d_in, const int* in_sizes, int n_in,
                              void* d_out, int out_size, void* d_ws, size_t ws_size,
                              hipStream_t stream) {
    const float* logits = (const float*)d_in[0];
    // d_in[1] (target) is unused by the reference computation.
    float* ws  = (float*)d_ws;
    float* out = (float*)d_out;

    cl_init_ws<<<1, 256, 0, stream>>>(ws);

    const long long total_pixels = (long long)NSMP * HW;       // 2,097,152
    const int blocks = (int)(total_pixels / 4 / 256);          // 2048
    cl_main<<<blocks, 256, 0, stream>>>(logits, ws);

    cl_final<<<1, 128, 0, stream>>>(ws, out);
}

// Round 2
// 55.280 us; speedup vs baseline: 1.0659x; 1.0659x over previous
//
#include <hip/hip_runtime.h>

// Problem constants (from reference setup_inputs):
//   logits: (N=4, C=19, H=512, W=1024) float32, target unused.
#define NCLS 19
#define NSMP 4
#define HW   (512 * 1024)
#define NSEG (NSMP * NCLS)   // 76 segments

// ws layout (floats): [0..NSEG) = S1, [NSEG..2*NSEG) = S2, [2*NSEG..3*NSEG) = cnt
__global__ void cl_init_ws(float* ws) {
    int i = threadIdx.x;
    if (i < 3 * NSEG) ws[i] = 0.0f;
}

__global__ __launch_bounds__(256) void cl_main(const float* __restrict__ logits,
                                               float* __restrict__ ws) {
    __shared__ float sS1[NCLS];
    __shared__ float sS2[NCLS];
    __shared__ float sCnt[NCLS];
    const int tid = threadIdx.x;
    if (tid < NCLS) { sS1[tid] = 0.0f; sS2[tid] = 0.0f; sCnt[tid] = 0.0f; }
    __syncthreads();

    // 4 consecutive pixels per thread; 1024 pixels per block.
    // HW % 1024 == 0, so every block lies within a single sample n.
    const long long p   = ((long long)blockIdx.x * 256 + tid) * 4;  // pixel idx in N*HW
    const int       n   = (int)(p / HW);
    const long long off = p - (long long)n * HW;
    const float* base = logits + (size_t)n * NCLS * HW + off;

    // ---- Phase 1: issue ALL 19 channel loads (statically indexed -> registers,
    // 19 global_load_dwordx4 in flight per wave). ----
    float4 v[NCLS];
    #pragma unroll
    for (int c = 0; c < NCLS; ++c) {
        v[c] = *(const float4*)(base + (size_t)c * HW);
    }
    // Keep the scheduler from sinking loads into the compute phase.
    asm volatile("" ::: "memory");

    // ---- Phase 2: per-pixel s1/s2/argmax over channels. ----
    float s1[4], s2[4], mv[4];
    int   mi[4];
    {
        const float a0[4] = {v[0].x, v[0].y, v[0].z, v[0].w};
        #pragma unroll
        for (int j = 0; j < 4; ++j) {
            s1[j] = a0[j];
            s2[j] = a0[j] * a0[j];
            mv[j] = a0[j];
            mi[j] = 0;
        }
    }
    #pragma unroll
    for (int c = 1; c < NCLS; ++c) {
        const float a[4] = {v[c].x, v[c].y, v[c].z, v[c].w};
        #pragma unroll
        for (int j = 0; j < 4; ++j) {
            s1[j] += a[j];
            s2[j] += a[j] * a[j];
            if (a[j] > mv[j]) { mv[j] = a[j]; mi[j] = c; }  // strict > keeps first-index argmax
        }
    }

    #pragma unroll
    for (int j = 0; j < 4; ++j) {
        atomicAdd(&sS1[mi[j]],  s1[j]);
        atomicAdd(&sS2[mi[j]],  s2[j]);
        atomicAdd(&sCnt[mi[j]], 1.0f);
    }
    __syncthreads();

    if (tid < NCLS) {
        const int seg = n * NCLS + tid;
        atomicAdd(&ws[seg],            sS1[tid]);
        atomicAdd(&ws[NSEG + seg],     sS2[tid]);
        atomicAdd(&ws[2 * NSEG + seg], sCnt[tid]);
    }
}

__global__ void cl_final(const float* __restrict__ ws, float* __restrict__ out) {
    __shared__ float red[128];
    const int i = threadIdx.x;
    float v = 0.0f;
    if (i < NSEG) {
        const float S1  = ws[i];
        const float S2  = ws[NSEG + i];
        const float cnt = ws[2 * NSEG + i];
        const float K   = fmaxf(cnt, 1.0f) * (float)NCLS;
        const float sq  = fmaxf(S2 - S1 * S1 / K, 0.0f);
        v = (cnt > 0.0f) ? sqrtf(sq) : 0.0f;
    }
    red[i] = v;
    __syncthreads();
    #pragma unroll
    for (int s = 64; s > 0; s >>= 1) {
        if (i < s) red[i] += red[i + s];
        __syncthreads();
    }
    if (i == 0) out[0] = red[0] / (float)NSMP;
}

extern "C" void kernel_launch(void* const* d_in, const int* in_sizes, int n_in,
                              void* d_out, int out_size, void* d_ws, size_t ws_size,
                              hipStream_t stream) {
    const float* logits = (const float*)d_in[0];
    // d_in[1] (target) is unused by the reference computation.
    float* ws  = (float*)d_ws;
    float* out = (float*)d_out;

    cl_init_ws<<<1, 256, 0, stream>>>(ws);

    const long long total_pixels = (long long)NSMP * HW;       // 2,097,152
    const int blocks = (int)(total_pixels / 4 / 256);          // 2048
    cl_main<<<blocks, 256, 0, stream>>>(logits, ws);

    cl_final<<<1, 128, 0, stream>>>(ws, out);
}